// Round 11
// baseline (232.154 us; speedup 1.0000x reference)
//
#include <hip/hip_runtime.h>
#include <hip/hip_bf16.h>

#define N_NODES 50000
#define N_EDGES 800000
#define DIM 128
#define NUM_REL 200
#define NREL2 (2 * NUM_REL)
#define SCAN_BLK 512
#define SCAN_NBLK ((N_NODES + SCAN_BLK - 1) / SCAN_BLK)  // 98
#define NROWG (N_NODES / 16)   // 3125 row groups of 16 nodes
#define NWAVES (6 * NROWG)     // 18750 waves: one (rg, cb) pair each
#define NODES_PER_XCD (N_NODES / 8)  // 6250
// Zero-row padding: EEb row 100000 and Rb row 400 are all-zero.
#define ZROW (2 * N_NODES)
#define ZREL NREL2
#define ZPAY (ZROW | (ZREL << 17))

typedef __bf16 bf16x8 __attribute__((ext_vector_type(8)));
typedef float f32x4 __attribute__((ext_vector_type(4)));

// ---------------------------------------------------------------------------
// Kernel A: merged relation table Rb[401][128] in bf16 (W_O rel-half +b for
// t<200, W_I rel-half +b else; row 400 zeroed by memset) and rel_new output
// (rel_emb @ W_R^T + b_R, fp32).
// ---------------------------------------------------------------------------
__global__ void rel_tables_kernel(const float* __restrict__ rel_emb,
                                  const float* __restrict__ W_O_w,
                                  const float* __restrict__ W_O_b,
                                  const float* __restrict__ W_I_w,
                                  const float* __restrict__ W_I_b,
                                  const float* __restrict__ W_R_w,
                                  const float* __restrict__ W_R_b,
                                  __bf16* __restrict__ Rb,
                                  float* __restrict__ rel_new) {
    __shared__ float row[DIM];
    const int t = blockIdx.x;   // 0..399
    const int j = threadIdx.x;  // 0..127
    row[j] = rel_emb[t * DIM + j];
    __syncthreads();

    const bool fwd = (t < NUM_REL);
    const float* __restrict__ wSel = (fwd ? W_O_w : W_I_w) + j * (2 * DIM);
    const float* __restrict__ wR = W_R_w + j * DIM;

    float aSel = 0.f, aR = 0.f;
#pragma unroll 8
    for (int k = 0; k < DIM; ++k) {
        const float e = row[k];
        aSel += e * wSel[k];
        aR += e * wR[k];
    }
    Rb[t * DIM + j] = (__bf16)(aSel + (fwd ? W_O_b[j] : W_I_b[j]));
    rel_new[t * DIM + j] = aR + W_R_b[j];
}

// ---------------------------------------------------------------------------
// Weight prep: merged WT[384][128] (row j: j<128 -> W_O ent-half row j;
// j<256 -> W_I ent-half; else W_S) split into bf16 hi/lo.
// ---------------------------------------------------------------------------
__global__ void __launch_bounds__(256)
wt_build_kernel(const float* __restrict__ W_O_w, const float* __restrict__ W_I_w,
                const float* __restrict__ W_S_w,
                __bf16* __restrict__ WTh, __bf16* __restrict__ WTl) {
    const int idx = blockIdx.x * 256 + threadIdx.x;
    if (idx >= 384 * DIM) return;
    const int j = idx >> 7;
    const int k = idx & 127;
    float v;
    if (j < 128) v = W_O_w[j * (2 * DIM) + DIM + k];
    else if (j < 256) v = W_I_w[(j - 128) * (2 * DIM) + DIM + k];
    else v = W_S_w[(j - 256) * DIM + k];
    const __bf16 h = (__bf16)v;
    WTh[idx] = h;
    WTl[idx] = (__bf16)(v - (float)h);
}

// ---------------------------------------------------------------------------
// Kernel B (v10): MFMA bf16-split GEMM, B-register-resident, ONE row-group
// per wave.  18750 waves (vs v9's 3750) -> ~18 waves/SIMD queued so resident
// waves overlap each other's load windows (v9 was latency-bound at 3.7).
// B fragments (hi+lo, 32 x bf16x8 = 128 VGPR) + A (8 float4) all issued in
// one load window, then 48 register-only MFMAs.
// ---------------------------------------------------------------------------
#define REP4(F) F(0) F(1) F(2) F(3)

__global__ void __launch_bounds__(256, 1)
mfma_gemm_kernel(const float* __restrict__ ent,
                 const __bf16* __restrict__ WTh, const __bf16* __restrict__ WTl,
                 const float* __restrict__ W_S_b,
                 __bf16* __restrict__ EEb, float* __restrict__ ent_S) {
    const int w = blockIdx.x * 4 + (threadIdx.x >> 6);
    if (w >= NWAVES) return;
    const int cb = w % 6;
    const int rg = w / 6;
    const int l = threadIdx.x & 63;
    const int r16 = l & 15;  // row (A) / col (B,D)
    const int kg = l >> 4;   // k-subgroup 0..3

    const int c0 = cb * 64;
    const __bf16* __restrict__ bb = WTh + (size_t)(c0 + r16) * DIM + kg * 8;
    const ptrdiff_t dlo = WTl - WTh;

#define BDECL(s, ks)                                                           \
    const bf16x8 Bh_##s##_##ks =                                               \
        *(const bf16x8*)(bb + (size_t)(s) * 16 * DIM + (ks) * 32);             \
    const bf16x8 Bl_##s##_##ks =                                               \
        *(const bf16x8*)(bb + dlo + (size_t)(s) * 16 * DIM + (ks) * 32);
#define BROW(s) BDECL(s, 0) BDECL(s, 1) BDECL(s, 2) BDECL(s, 3)
    REP4(BROW)
#undef BROW
#undef BDECL

    const float* __restrict__ aptr = ent + (size_t)(rg * 16 + r16) * DIM + kg * 8;
#define ADECL(ks)                                                              \
    bf16x8 ah##ks, al##ks;                                                     \
    {                                                                          \
        const float4 v0 = *(const float4*)(aptr + (ks) * 32);                  \
        const float4 v1 = *(const float4*)(aptr + (ks) * 32 + 4);              \
        const float xs[8] = {v0.x, v0.y, v0.z, v0.w, v1.x, v1.y, v1.z, v1.w};  \
        _Pragma("unroll") for (int i = 0; i < 8; ++i) {                        \
            const __bf16 h = (__bf16)xs[i];                                    \
            ah##ks[i] = h;                                                     \
            al##ks[i] = (__bf16)(xs[i] - (float)h);                            \
        }                                                                      \
    }
    REP4(ADECL)
#undef ADECL

    f32x4 p0 = {0.f, 0.f, 0.f, 0.f}, q0 = {0.f, 0.f, 0.f, 0.f};
    f32x4 p1 = {0.f, 0.f, 0.f, 0.f}, q1 = {0.f, 0.f, 0.f, 0.f};
    f32x4 p2 = {0.f, 0.f, 0.f, 0.f}, q2 = {0.f, 0.f, 0.f, 0.f};
    f32x4 p3 = {0.f, 0.f, 0.f, 0.f}, q3 = {0.f, 0.f, 0.f, 0.f};

#define KS(ks)                                                                 \
    p0 = __builtin_amdgcn_mfma_f32_16x16x32_bf16(ah##ks, Bh_0_##ks, p0, 0, 0, 0); \
    p1 = __builtin_amdgcn_mfma_f32_16x16x32_bf16(ah##ks, Bh_1_##ks, p1, 0, 0, 0); \
    p2 = __builtin_amdgcn_mfma_f32_16x16x32_bf16(ah##ks, Bh_2_##ks, p2, 0, 0, 0); \
    p3 = __builtin_amdgcn_mfma_f32_16x16x32_bf16(ah##ks, Bh_3_##ks, p3, 0, 0, 0); \
    q0 = __builtin_amdgcn_mfma_f32_16x16x32_bf16(al##ks, Bh_0_##ks, q0, 0, 0, 0); \
    q1 = __builtin_amdgcn_mfma_f32_16x16x32_bf16(al##ks, Bh_1_##ks, q1, 0, 0, 0); \
    q2 = __builtin_amdgcn_mfma_f32_16x16x32_bf16(al##ks, Bh_2_##ks, q2, 0, 0, 0); \
    q3 = __builtin_amdgcn_mfma_f32_16x16x32_bf16(al##ks, Bh_3_##ks, q3, 0, 0, 0); \
    q0 = __builtin_amdgcn_mfma_f32_16x16x32_bf16(ah##ks, Bl_0_##ks, q0, 0, 0, 0); \
    q1 = __builtin_amdgcn_mfma_f32_16x16x32_bf16(ah##ks, Bl_1_##ks, q1, 0, 0, 0); \
    q2 = __builtin_amdgcn_mfma_f32_16x16x32_bf16(ah##ks, Bl_2_##ks, q2, 0, 0, 0); \
    q3 = __builtin_amdgcn_mfma_f32_16x16x32_bf16(ah##ks, Bl_3_##ks, q3, 0, 0, 0);
    REP4(KS)
#undef KS

    const int orow = rg * 16 + kg * 4;
    const int colb = (cb & 1) * 64;
    if (cb < 4) {
        __bf16* __restrict__ obb = EEb + ((cb < 2) ? 0 : (size_t)N_NODES * DIM);
#define ST(s, P, Q)                                                            \
        {                                                                      \
            const int col = colb + (s) * 16 + r16;                             \
            const f32x4 a = P + Q;                                             \
            obb[(size_t)(orow + 0) * DIM + col] = (__bf16)a[0];                \
            obb[(size_t)(orow + 1) * DIM + col] = (__bf16)a[1];                \
            obb[(size_t)(orow + 2) * DIM + col] = (__bf16)a[2];                \
            obb[(size_t)(orow + 3) * DIM + col] = (__bf16)a[3];                \
        }
        ST(0, p0, q0) ST(1, p1, q1) ST(2, p2, q2) ST(3, p3, q3)
#undef ST
    } else {
#define ST(s, P, Q)                                                            \
        {                                                                      \
            const int col = colb + (s) * 16 + r16;                             \
            const float bs = W_S_b[col];                                       \
            const f32x4 a = P + Q;                                             \
            ent_S[(size_t)(orow + 0) * DIM + col] = a[0] + bs;                 \
            ent_S[(size_t)(orow + 1) * DIM + col] = a[1] + bs;                 \
            ent_S[(size_t)(orow + 2) * DIM + col] = a[2] + bs;                 \
            ent_S[(size_t)(orow + 3) * DIM + col] = a[3] + bs;                 \
        }
        ST(0, p0, q0) ST(1, p1, q1) ST(2, p2, q2) ST(3, p3, q3)
#undef ST
    }
}

// ---------------------------------------------------------------------------
// CSR construction: histogram -> 3-phase exclusive scan -> fill.
// ---------------------------------------------------------------------------
__global__ void __launch_bounds__(256)
hist_kernel(const int* __restrict__ dst, int* __restrict__ counts) {
    const int e = blockIdx.x * 256 + threadIdx.x;
    if (e < N_EDGES) atomicAdd(&counts[dst[e]], 1);
}

__global__ void __launch_bounds__(SCAN_BLK)
scan1_kernel(const int* __restrict__ counts, int* __restrict__ offs,
             int* __restrict__ bsum) {
    __shared__ int tmp[SCAN_BLK];
    const int i = blockIdx.x * SCAN_BLK + threadIdx.x;
    const int v = (i < N_NODES) ? counts[i] : 0;
    tmp[threadIdx.x] = v;
    __syncthreads();
    for (int off = 1; off < SCAN_BLK; off <<= 1) {
        const int t = (threadIdx.x >= off) ? tmp[threadIdx.x - off] : 0;
        __syncthreads();
        tmp[threadIdx.x] += t;
        __syncthreads();
    }
    if (i < N_NODES) offs[i] = tmp[threadIdx.x] - v;  // exclusive
    if (threadIdx.x == SCAN_BLK - 1) bsum[blockIdx.x] = tmp[SCAN_BLK - 1];
}

__global__ void __launch_bounds__(128)
scan2_kernel(int* __restrict__ bsum) {
    __shared__ int tmp[128];
    const int i = threadIdx.x;
    const int v = (i < SCAN_NBLK) ? bsum[i] : 0;
    tmp[i] = v;
    __syncthreads();
    for (int off = 1; off < 128; off <<= 1) {
        const int tv = (i >= off) ? tmp[i - off] : 0;
        __syncthreads();
        tmp[i] += tv;
        __syncthreads();
    }
    if (i < SCAN_NBLK) bsum[i] = tmp[i] - v;  // exclusive
}

// scan3 also seeds cursor = offs so fill's atomicAdd returns absolute slots.
__global__ void __launch_bounds__(SCAN_BLK)
scan3_kernel(int* __restrict__ offs, const int* __restrict__ bsum,
             int* __restrict__ cursor) {
    const int i = blockIdx.x * SCAN_BLK + threadIdx.x;
    if (i < N_NODES) {
        const int v = offs[i] + bsum[blockIdx.x];
        offs[i] = v;
        cursor[i] = v;
    }
}

// ---------------------------------------------------------------------------
// Fill v2: XCD-range-partitioned scatter.  Block b: edge chunk b>>3, node
// range r = b&7 (round-robin dispatch puts equal-r blocks on one XCD, so
// each sp/cursor cache line is written by a single XCD -> write amp ~1
// instead of the 17x seen in v1).  Edges read 8x (L3-served).
// Payload: row(17b) | etype<<17 (9b).  N_EDGES = 3125*256 exactly.
// ---------------------------------------------------------------------------
__global__ void __launch_bounds__(256)
fill_kernel(const int* __restrict__ src, const int* __restrict__ dst,
            const int* __restrict__ et, int* __restrict__ cursor,
            int* __restrict__ sp) {
    const int b = blockIdx.x;
    const int r = b & 7;
    const int e = (b >> 3) * 256 + threadIdx.x;
    const int d = dst[e];
    const int rlo = r * NODES_PER_XCD;
    if ((unsigned)(d - rlo) < (unsigned)NODES_PER_XCD) {
        const int t = et[e];
        const int row = src[e] + ((t < NUM_REL) ? 0 : N_NODES);
        const int pos = atomicAdd(&cursor[d], 1);
        sp[pos] = row | (t << 17);
    }
}

// ---------------------------------------------------------------------------
// Gather-reduce v3: one wave per node, FOUR edges per iteration.
// Quarter-wave q = l>>4 handles edge i+q; lane m = l&15 covers 16 B (8 bf16
// cols) of the 256 B row via uint4 loads.  Invalid slots hit the all-zero
// pad rows -> branch-free.  Two-level shfl_xor(16/32) reduce, fused
// finalize: out = ent_S + acc / max(deg,1), 2x float4 store.
// ---------------------------------------------------------------------------
__global__ void __launch_bounds__(256)
gather_kernel(const int* __restrict__ offs, const int* __restrict__ counts,
              const int* __restrict__ sp, const __bf16* __restrict__ EEb,
              const __bf16* __restrict__ Rb, const float* __restrict__ ent_S,
              float* __restrict__ out_ent) {
    const int node = blockIdx.x * 4 + (threadIdx.x >> 6);
    if (node >= N_NODES) return;
    const int l = threadIdx.x & 63;
    const int q = l >> 4;   // edge slot 0..3
    const int m = l & 15;   // 16B piece of the row

    const int beg = offs[node];
    const int cnt = counts[node];

    float a0 = 0.f, a1 = 0.f, a2 = 0.f, a3 = 0.f;
    float a4 = 0.f, a5 = 0.f, a6 = 0.f, a7 = 0.f;
    const char* __restrict__ Eb = (const char*)EEb + 16 * m;
    const char* __restrict__ Rp = (const char*)Rb + 16 * m;

    for (int base = 0; base < cnt; base += 64) {
        const int kk = min(64, cnt - base);
        const int myp = (base + l < cnt) ? sp[beg + base + l] : ZPAY;
#pragma unroll 2
        for (int i = 0; i < kk; i += 4) {
            const int p = __shfl(myp, i + q);
            const unsigned eoff = (unsigned)(p & 0x1FFFF) << 8;
            const unsigned roff = ((unsigned)p >> 17) << 8;
            const uint4 ev = *(const uint4*)(Eb + eoff);
            const uint4 rv = *(const uint4*)(Rp + roff);
            a0 += __uint_as_float(ev.x << 16) + __uint_as_float(rv.x << 16);
            a1 += __uint_as_float(ev.x & 0xffff0000u) +
                  __uint_as_float(rv.x & 0xffff0000u);
            a2 += __uint_as_float(ev.y << 16) + __uint_as_float(rv.y << 16);
            a3 += __uint_as_float(ev.y & 0xffff0000u) +
                  __uint_as_float(rv.y & 0xffff0000u);
            a4 += __uint_as_float(ev.z << 16) + __uint_as_float(rv.z << 16);
            a5 += __uint_as_float(ev.z & 0xffff0000u) +
                  __uint_as_float(rv.z & 0xffff0000u);
            a6 += __uint_as_float(ev.w << 16) + __uint_as_float(rv.w << 16);
            a7 += __uint_as_float(ev.w & 0xffff0000u) +
                  __uint_as_float(rv.w & 0xffff0000u);
        }
    }

#define RED(A) A += __shfl_xor(A, 16); A += __shfl_xor(A, 32);
    RED(a0) RED(a1) RED(a2) RED(a3) RED(a4) RED(a5) RED(a6) RED(a7)
#undef RED

    if (l < 16) {
        const float inv = 1.0f / fmaxf((float)cnt, 1.0f);
        const float* sp_ = ent_S + (size_t)node * DIM + 8 * m;
        const float4 s0 = *(const float4*)(sp_);
        const float4 s1 = *(const float4*)(sp_ + 4);
        float4 o0, o1;
        o0.x = s0.x + a0 * inv;
        o0.y = s0.y + a1 * inv;
        o0.z = s0.z + a2 * inv;
        o0.w = s0.w + a3 * inv;
        o1.x = s1.x + a4 * inv;
        o1.y = s1.y + a5 * inv;
        o1.z = s1.z + a6 * inv;
        o1.w = s1.w + a7 * inv;
        float* op = out_ent + (size_t)node * DIM + 8 * m;
        *(float4*)(op) = o0;
        *(float4*)(op + 4) = o1;
    }
}

extern "C" void kernel_launch(void* const* d_in, const int* in_sizes, int n_in,
                              void* d_out, int out_size, void* d_ws, size_t ws_size,
                              hipStream_t stream) {
    const int* src = (const int*)d_in[0];
    const int* dst = (const int*)d_in[1];
    const int* et = (const int*)d_in[2];
    const float* ent_emb = (const float*)d_in[3];
    const float* rel_emb = (const float*)d_in[4];
    const float* W_O_w = (const float*)d_in[5];
    const float* W_O_b = (const float*)d_in[6];
    const float* W_I_w = (const float*)d_in[7];
    const float* W_I_b = (const float*)d_in[8];
    const float* W_S_w = (const float*)d_in[9];
    const float* W_S_b = (const float*)d_in[10];
    const float* W_R_w = (const float*)d_in[11];
    const float* W_R_b = (const float*)d_in[12];

    float* out_ent = (float*)d_out;                    // [50000*128]
    float* out_rel = out_ent + (size_t)N_NODES * DIM;  // [400*128]

    // Workspace layout (floats):
    // ent_S | EEb(bf16, 100001 rows) | Rb(bf16, 401 rows) | WTh | WTl | ints
    float* wsf = (float*)d_ws;
    float* ent_S = wsf;
    wsf += (size_t)N_NODES * DIM;            // 6.4M f
    __bf16* EEb = (__bf16*)wsf;
    wsf += ((size_t)(2 * N_NODES + 1) * DIM + 1) / 2;  // 100001 rows bf16
    __bf16* Rb = (__bf16*)wsf;
    wsf += (size_t)(NREL2 + 1) * DIM / 2;    // 401 rows bf16
    __bf16* WTh = (__bf16*)wsf;
    wsf += 384 * DIM / 2;
    __bf16* WTl = (__bf16*)wsf;
    wsf += 384 * DIM / 2;
    int* counts = (int*)wsf;
    int* cursor = counts + N_NODES;
    int* bsum = cursor + N_NODES;
    int* offs = bsum + 128;
    int* sp = offs + N_NODES;
    // total ~56 MB

    hipMemsetAsync(counts, 0, N_NODES * sizeof(int), stream);
    // Zero pad rows (EEb row 100000, Rb row 400).
    hipMemsetAsync(EEb + (size_t)ZROW * DIM, 0, DIM * sizeof(__bf16), stream);
    hipMemsetAsync(Rb + (size_t)ZREL * DIM, 0, DIM * sizeof(__bf16), stream);

    rel_tables_kernel<<<NREL2, DIM, 0, stream>>>(rel_emb, W_O_w, W_O_b, W_I_w, W_I_b,
                                                 W_R_w, W_R_b, Rb, out_rel);

    wt_build_kernel<<<(384 * DIM + 255) / 256, 256, 0, stream>>>(
        W_O_w, W_I_w, W_S_w, WTh, WTl);

    mfma_gemm_kernel<<<(NWAVES + 3) / 4, 256, 0, stream>>>(
        ent_emb, WTh, WTl, W_S_b, EEb, ent_S);

    hist_kernel<<<(N_EDGES + 255) / 256, 256, 0, stream>>>(dst, counts);
    scan1_kernel<<<SCAN_NBLK, SCAN_BLK, 0, stream>>>(counts, offs, bsum);
    scan2_kernel<<<1, 128, 0, stream>>>(bsum);
    scan3_kernel<<<SCAN_NBLK, SCAN_BLK, 0, stream>>>(offs, bsum, cursor);
    fill_kernel<<<(N_EDGES / 256) * 8, 256, 0, stream>>>(src, dst, et, cursor, sp);

    gather_kernel<<<(N_NODES + 3) / 4, 256, 0, stream>>>(offs, counts, sp, EEb, Rb,
                                                         ent_S, out_ent);
}

// Round 12
// 190.915 us; speedup vs baseline: 1.2160x; 1.2160x over previous
//
#include <hip/hip_runtime.h>
#include <hip/hip_bf16.h>

#define N_NODES 50000
#define N_EDGES 800000
#define DIM 128
#define NUM_REL 200
#define NREL2 (2 * NUM_REL)
#define SCAN_BLK 512
#define SCAN_NBLK ((N_NODES + SCAN_BLK - 1) / SCAN_BLK)  // 98
#define NROWG (N_NODES / 16)   // 3125 row groups of 16 nodes
#define RG_PER_WAVE 5
#define RG_PER_BLK 20          // 4 waves x 5 rgs
#define NBLK_X ((NROWG + RG_PER_BLK - 1) / RG_PER_BLK)  // 157
#define NODES_PER_XCD (N_NODES / 8)  // 6250
// Zero-row padding: EEb row 100000 and Rb row 400 are all-zero.
#define ZROW (2 * N_NODES)
#define ZREL NREL2
#define ZPAY (ZROW | (ZREL << 17))

typedef __bf16 bf16x8 __attribute__((ext_vector_type(8)));
typedef float f32x4 __attribute__((ext_vector_type(4)));

// ---------------------------------------------------------------------------
// Kernel A: merged relation table Rb[401][128] in bf16 (W_O rel-half +b for
// t<200, W_I rel-half +b else; row 400 zeroed by memset) and rel_new output
// (rel_emb @ W_R^T + b_R, fp32).
// ---------------------------------------------------------------------------
__global__ void rel_tables_kernel(const float* __restrict__ rel_emb,
                                  const float* __restrict__ W_O_w,
                                  const float* __restrict__ W_O_b,
                                  const float* __restrict__ W_I_w,
                                  const float* __restrict__ W_I_b,
                                  const float* __restrict__ W_R_w,
                                  const float* __restrict__ W_R_b,
                                  __bf16* __restrict__ Rb,
                                  float* __restrict__ rel_new) {
    __shared__ float row[DIM];
    const int t = blockIdx.x;   // 0..399
    const int j = threadIdx.x;  // 0..127
    row[j] = rel_emb[t * DIM + j];
    __syncthreads();

    const bool fwd = (t < NUM_REL);
    const float* __restrict__ wSel = (fwd ? W_O_w : W_I_w) + j * (2 * DIM);
    const float* __restrict__ wR = W_R_w + j * DIM;

    float aSel = 0.f, aR = 0.f;
#pragma unroll 8
    for (int k = 0; k < DIM; ++k) {
        const float e = row[k];
        aSel += e * wSel[k];
        aR += e * wR[k];
    }
    Rb[t * DIM + j] = (__bf16)(aSel + (fwd ? W_O_b[j] : W_I_b[j]));
    rel_new[t * DIM + j] = aR + W_R_b[j];
}

// ---------------------------------------------------------------------------
// Weight prep: merged WT[384][128] (row j: j<128 -> W_O ent-half row j;
// j<256 -> W_I ent-half; else W_S) split into bf16 hi/lo.
// ---------------------------------------------------------------------------
__global__ void __launch_bounds__(256)
wt_build_kernel(const float* __restrict__ W_O_w, const float* __restrict__ W_I_w,
                const float* __restrict__ W_S_w,
                __bf16* __restrict__ WTh, __bf16* __restrict__ WTl) {
    const int idx = blockIdx.x * 256 + threadIdx.x;
    if (idx >= 384 * DIM) return;
    const int j = idx >> 7;
    const int k = idx & 127;
    float v;
    if (j < 128) v = W_O_w[j * (2 * DIM) + DIM + k];
    else if (j < 256) v = W_I_w[(j - 128) * (2 * DIM) + DIM + k];
    else v = W_S_w[(j - 256) * DIM + k];
    const __bf16 h = (__bf16)v;
    WTh[idx] = h;
    WTl[idx] = (__bf16)(v - (float)h);
}

// ---------------------------------------------------------------------------
// Kernel B (v11): MFMA bf16-split GEMM.  v9 structure (RG_PER_WAVE=5, proven
// 57us) with ONE change: all 4 waves of a block share the SAME column block
// (cb = blockIdx.y) and take different row-groups.  The compiler re-loads B
// per use (it never keeps 128+ VGPR of B resident - measured VGPR 56..108);
// with a single 4KB hi+lo B tile per block those reloads are L1 hits
// (~50cyc) instead of the L2 round-trips (~250cyc) that serialized v9/v10.
// ---------------------------------------------------------------------------
#define REP4(F) F(0) F(1) F(2) F(3)

__global__ void __launch_bounds__(256, 1)
mfma_gemm_kernel(const float* __restrict__ ent,
                 const __bf16* __restrict__ WTh, const __bf16* __restrict__ WTl,
                 const float* __restrict__ W_S_b,
                 __bf16* __restrict__ EEb, float* __restrict__ ent_S) {
    const int wv = threadIdx.x >> 6;
    const int cb = blockIdx.y;                       // 0..5, block-uniform
    const int rg0 = blockIdx.x * RG_PER_BLK + wv * RG_PER_WAVE;
    const int l = threadIdx.x & 63;
    const int r16 = l & 15;  // row (A) / col (B,D)
    const int kg = l >> 4;   // k-subgroup 0..3

    const int c0 = cb * 64;
    const __bf16* __restrict__ bb = WTh + (size_t)(c0 + r16) * DIM + kg * 8;
    const ptrdiff_t dlo = WTl - WTh;

    // B fragment loads (compiler will re-issue these per use; they are L1-hot).
#define BDECL(s, ks)                                                           \
    const bf16x8 Bh_##s##_##ks =                                               \
        *(const bf16x8*)(bb + (size_t)(s) * 16 * DIM + (ks) * 32);             \
    const bf16x8 Bl_##s##_##ks =                                               \
        *(const bf16x8*)(bb + dlo + (size_t)(s) * 16 * DIM + (ks) * 32);
#define BROW(s) BDECL(s, 0) BDECL(s, 1) BDECL(s, 2) BDECL(s, 3)
    REP4(BROW)
#undef BROW
#undef BDECL

    const int colb = (cb & 1) * 64;
    __bf16* __restrict__ obb =
        (cb < 4) ? (EEb + ((cb < 2) ? 0 : (size_t)N_NODES * DIM)) : (__bf16*)0;

#pragma unroll 1
    for (int rg = rg0; rg < rg0 + RG_PER_WAVE; ++rg) {
        if (rg >= NROWG) break;
        const float* __restrict__ aptr = ent + (size_t)(rg * 16 + r16) * DIM + kg * 8;
#define ADECL(ks)                                                              \
        bf16x8 ah##ks, al##ks;                                                 \
        {                                                                      \
            const float4 v0 = *(const float4*)(aptr + (ks) * 32);              \
            const float4 v1 = *(const float4*)(aptr + (ks) * 32 + 4);          \
            const float xs[8] = {v0.x, v0.y, v0.z, v0.w, v1.x, v1.y, v1.z, v1.w}; \
            _Pragma("unroll") for (int i = 0; i < 8; ++i) {                    \
                const __bf16 h = (__bf16)xs[i];                                \
                ah##ks[i] = h;                                                 \
                al##ks[i] = (__bf16)(xs[i] - (float)h);                        \
            }                                                                  \
        }
        REP4(ADECL)
#undef ADECL

        f32x4 p0 = {0.f, 0.f, 0.f, 0.f}, q0 = {0.f, 0.f, 0.f, 0.f};
        f32x4 p1 = {0.f, 0.f, 0.f, 0.f}, q1 = {0.f, 0.f, 0.f, 0.f};
        f32x4 p2 = {0.f, 0.f, 0.f, 0.f}, q2 = {0.f, 0.f, 0.f, 0.f};
        f32x4 p3 = {0.f, 0.f, 0.f, 0.f}, q3 = {0.f, 0.f, 0.f, 0.f};

#define KS(ks)                                                                 \
        p0 = __builtin_amdgcn_mfma_f32_16x16x32_bf16(ah##ks, Bh_0_##ks, p0, 0, 0, 0); \
        p1 = __builtin_amdgcn_mfma_f32_16x16x32_bf16(ah##ks, Bh_1_##ks, p1, 0, 0, 0); \
        p2 = __builtin_amdgcn_mfma_f32_16x16x32_bf16(ah##ks, Bh_2_##ks, p2, 0, 0, 0); \
        p3 = __builtin_amdgcn_mfma_f32_16x16x32_bf16(ah##ks, Bh_3_##ks, p3, 0, 0, 0); \
        q0 = __builtin_amdgcn_mfma_f32_16x16x32_bf16(al##ks, Bh_0_##ks, q0, 0, 0, 0); \
        q1 = __builtin_amdgcn_mfma_f32_16x16x32_bf16(al##ks, Bh_1_##ks, q1, 0, 0, 0); \
        q2 = __builtin_amdgcn_mfma_f32_16x16x32_bf16(al##ks, Bh_2_##ks, q2, 0, 0, 0); \
        q3 = __builtin_amdgcn_mfma_f32_16x16x32_bf16(al##ks, Bh_3_##ks, q3, 0, 0, 0); \
        q0 = __builtin_amdgcn_mfma_f32_16x16x32_bf16(ah##ks, Bl_0_##ks, q0, 0, 0, 0); \
        q1 = __builtin_amdgcn_mfma_f32_16x16x32_bf16(ah##ks, Bl_1_##ks, q1, 0, 0, 0); \
        q2 = __builtin_amdgcn_mfma_f32_16x16x32_bf16(ah##ks, Bl_2_##ks, q2, 0, 0, 0); \
        q3 = __builtin_amdgcn_mfma_f32_16x16x32_bf16(ah##ks, Bl_3_##ks, q3, 0, 0, 0);
        REP4(KS)
#undef KS

        const int orow = rg * 16 + kg * 4;
        if (cb < 4) {
#define ST(s, P, Q)                                                            \
            {                                                                  \
                const int col = colb + (s) * 16 + r16;                         \
                const f32x4 a = P + Q;                                         \
                obb[(size_t)(orow + 0) * DIM + col] = (__bf16)a[0];            \
                obb[(size_t)(orow + 1) * DIM + col] = (__bf16)a[1];            \
                obb[(size_t)(orow + 2) * DIM + col] = (__bf16)a[2];            \
                obb[(size_t)(orow + 3) * DIM + col] = (__bf16)a[3];            \
            }
            ST(0, p0, q0) ST(1, p1, q1) ST(2, p2, q2) ST(3, p3, q3)
#undef ST
        } else {
#define ST(s, P, Q)                                                            \
            {                                                                  \
                const int col = colb + (s) * 16 + r16;                         \
                const float bs = W_S_b[col];                                   \
                const f32x4 a = P + Q;                                         \
                ent_S[(size_t)(orow + 0) * DIM + col] = a[0] + bs;             \
                ent_S[(size_t)(orow + 1) * DIM + col] = a[1] + bs;             \
                ent_S[(size_t)(orow + 2) * DIM + col] = a[2] + bs;             \
                ent_S[(size_t)(orow + 3) * DIM + col] = a[3] + bs;             \
            }
            ST(0, p0, q0) ST(1, p1, q1) ST(2, p2, q2) ST(3, p3, q3)
#undef ST
        }
    }
}

// ---------------------------------------------------------------------------
// CSR construction: histogram -> 3-phase exclusive scan -> fill.
// ---------------------------------------------------------------------------
__global__ void __launch_bounds__(256)
hist_kernel(const int* __restrict__ dst, int* __restrict__ counts) {
    const int e = blockIdx.x * 256 + threadIdx.x;
    if (e < N_EDGES) atomicAdd(&counts[dst[e]], 1);
}

__global__ void __launch_bounds__(SCAN_BLK)
scan1_kernel(const int* __restrict__ counts, int* __restrict__ offs,
             int* __restrict__ bsum) {
    __shared__ int tmp[SCAN_BLK];
    const int i = blockIdx.x * SCAN_BLK + threadIdx.x;
    const int v = (i < N_NODES) ? counts[i] : 0;
    tmp[threadIdx.x] = v;
    __syncthreads();
    for (int off = 1; off < SCAN_BLK; off <<= 1) {
        const int t = (threadIdx.x >= off) ? tmp[threadIdx.x - off] : 0;
        __syncthreads();
        tmp[threadIdx.x] += t;
        __syncthreads();
    }
    if (i < N_NODES) offs[i] = tmp[threadIdx.x] - v;  // exclusive
    if (threadIdx.x == SCAN_BLK - 1) bsum[blockIdx.x] = tmp[SCAN_BLK - 1];
}

__global__ void __launch_bounds__(128)
scan2_kernel(int* __restrict__ bsum) {
    __shared__ int tmp[128];
    const int i = threadIdx.x;
    const int v = (i < SCAN_NBLK) ? bsum[i] : 0;
    tmp[i] = v;
    __syncthreads();
    for (int off = 1; off < 128; off <<= 1) {
        const int tv = (i >= off) ? tmp[i - off] : 0;
        __syncthreads();
        tmp[i] += tv;
        __syncthreads();
    }
    if (i < SCAN_NBLK) bsum[i] = tmp[i] - v;  // exclusive
}

// scan3 also seeds cursor = offs so fill's atomicAdd returns absolute slots.
__global__ void __launch_bounds__(SCAN_BLK)
scan3_kernel(int* __restrict__ offs, const int* __restrict__ bsum,
             int* __restrict__ cursor) {
    const int i = blockIdx.x * SCAN_BLK + threadIdx.x;
    if (i < N_NODES) {
        const int v = offs[i] + bsum[blockIdx.x];
        offs[i] = v;
        cursor[i] = v;
    }
}

// ---------------------------------------------------------------------------
// Fill v2: XCD-range-partitioned scatter.  Block b: edge chunk b>>3, node
// range r = b&7 (round-robin dispatch puts equal-r blocks on one XCD, so
// each sp/cursor cache line is written by a single XCD).  Edges read 8x
// (L3-served).  Payload: row(17b) | etype<<17 (9b).
// ---------------------------------------------------------------------------
__global__ void __launch_bounds__(256)
fill_kernel(const int* __restrict__ src, const int* __restrict__ dst,
            const int* __restrict__ et, int* __restrict__ cursor,
            int* __restrict__ sp) {
    const int b = blockIdx.x;
    const int r = b & 7;
    const int e = (b >> 3) * 256 + threadIdx.x;
    const int d = dst[e];
    const int rlo = r * NODES_PER_XCD;
    if ((unsigned)(d - rlo) < (unsigned)NODES_PER_XCD) {
        const int t = et[e];
        const int row = src[e] + ((t < NUM_REL) ? 0 : N_NODES);
        const int pos = atomicAdd(&cursor[d], 1);
        sp[pos] = row | (t << 17);
    }
}

// ---------------------------------------------------------------------------
// Gather-reduce v3: one wave per node, FOUR edges per iteration.
// Quarter-wave q = l>>4 handles edge i+q; lane m = l&15 covers 16 B (8 bf16
// cols) of the 256 B row via uint4 loads.  Invalid slots hit the all-zero
// pad rows -> branch-free.  Two-level shfl_xor(16/32) reduce, fused
// finalize: out = ent_S + acc / max(deg,1), 2x float4 store.
// ---------------------------------------------------------------------------
__global__ void __launch_bounds__(256)
gather_kernel(const int* __restrict__ offs, const int* __restrict__ counts,
              const int* __restrict__ sp, const __bf16* __restrict__ EEb,
              const __bf16* __restrict__ Rb, const float* __restrict__ ent_S,
              float* __restrict__ out_ent) {
    const int node = blockIdx.x * 4 + (threadIdx.x >> 6);
    if (node >= N_NODES) return;
    const int l = threadIdx.x & 63;
    const int q = l >> 4;   // edge slot 0..3
    const int m = l & 15;   // 16B piece of the row

    const int beg = offs[node];
    const int cnt = counts[node];

    float a0 = 0.f, a1 = 0.f, a2 = 0.f, a3 = 0.f;
    float a4 = 0.f, a5 = 0.f, a6 = 0.f, a7 = 0.f;
    const char* __restrict__ Eb = (const char*)EEb + 16 * m;
    const char* __restrict__ Rp = (const char*)Rb + 16 * m;

    for (int base = 0; base < cnt; base += 64) {
        const int kk = min(64, cnt - base);
        const int myp = (base + l < cnt) ? sp[beg + base + l] : ZPAY;
#pragma unroll 2
        for (int i = 0; i < kk; i += 4) {
            const int p = __shfl(myp, i + q);
            const unsigned eoff = (unsigned)(p & 0x1FFFF) << 8;
            const unsigned roff = ((unsigned)p >> 17) << 8;
            const uint4 ev = *(const uint4*)(Eb + eoff);
            const uint4 rv = *(const uint4*)(Rp + roff);
            a0 += __uint_as_float(ev.x << 16) + __uint_as_float(rv.x << 16);
            a1 += __uint_as_float(ev.x & 0xffff0000u) +
                  __uint_as_float(rv.x & 0xffff0000u);
            a2 += __uint_as_float(ev.y << 16) + __uint_as_float(rv.y << 16);
            a3 += __uint_as_float(ev.y & 0xffff0000u) +
                  __uint_as_float(rv.y & 0xffff0000u);
            a4 += __uint_as_float(ev.z << 16) + __uint_as_float(rv.z << 16);
            a5 += __uint_as_float(ev.z & 0xffff0000u) +
                  __uint_as_float(rv.z & 0xffff0000u);
            a6 += __uint_as_float(ev.w << 16) + __uint_as_float(rv.w << 16);
            a7 += __uint_as_float(ev.w & 0xffff0000u) +
                  __uint_as_float(rv.w & 0xffff0000u);
        }
    }

#define RED(A) A += __shfl_xor(A, 16); A += __shfl_xor(A, 32);
    RED(a0) RED(a1) RED(a2) RED(a3) RED(a4) RED(a5) RED(a6) RED(a7)
#undef RED

    if (l < 16) {
        const float inv = 1.0f / fmaxf((float)cnt, 1.0f);
        const float* sp_ = ent_S + (size_t)node * DIM + 8 * m;
        const float4 s0 = *(const float4*)(sp_);
        const float4 s1 = *(const float4*)(sp_ + 4);
        float4 o0, o1;
        o0.x = s0.x + a0 * inv;
        o0.y = s0.y + a1 * inv;
        o0.z = s0.z + a2 * inv;
        o0.w = s0.w + a3 * inv;
        o1.x = s1.x + a4 * inv;
        o1.y = s1.y + a5 * inv;
        o1.z = s1.z + a6 * inv;
        o1.w = s1.w + a7 * inv;
        float* op = out_ent + (size_t)node * DIM + 8 * m;
        *(float4*)(op) = o0;
        *(float4*)(op + 4) = o1;
    }
}

extern "C" void kernel_launch(void* const* d_in, const int* in_sizes, int n_in,
                              void* d_out, int out_size, void* d_ws, size_t ws_size,
                              hipStream_t stream) {
    const int* src = (const int*)d_in[0];
    const int* dst = (const int*)d_in[1];
    const int* et = (const int*)d_in[2];
    const float* ent_emb = (const float*)d_in[3];
    const float* rel_emb = (const float*)d_in[4];
    const float* W_O_w = (const float*)d_in[5];
    const float* W_O_b = (const float*)d_in[6];
    const float* W_I_w = (const float*)d_in[7];
    const float* W_I_b = (const float*)d_in[8];
    const float* W_S_w = (const float*)d_in[9];
    const float* W_S_b = (const float*)d_in[10];
    const float* W_R_w = (const float*)d_in[11];
    const float* W_R_b = (const float*)d_in[12];

    float* out_ent = (float*)d_out;                    // [50000*128]
    float* out_rel = out_ent + (size_t)N_NODES * DIM;  // [400*128]

    // Workspace layout (floats):
    // ent_S | EEb(bf16, 100001 rows) | Rb(bf16, 401 rows) | WTh | WTl | ints
    float* wsf = (float*)d_ws;
    float* ent_S = wsf;
    wsf += (size_t)N_NODES * DIM;            // 6.4M f
    __bf16* EEb = (__bf16*)wsf;
    wsf += ((size_t)(2 * N_NODES + 1) * DIM + 1) / 2;  // 100001 rows bf16
    __bf16* Rb = (__bf16*)wsf;
    wsf += (size_t)(NREL2 + 1) * DIM / 2;    // 401 rows bf16
    __bf16* WTh = (__bf16*)wsf;
    wsf += 384 * DIM / 2;
    __bf16* WTl = (__bf16*)wsf;
    wsf += 384 * DIM / 2;
    int* counts = (int*)wsf;
    int* cursor = counts + N_NODES;
    int* bsum = cursor + N_NODES;
    int* offs = bsum + 128;
    int* sp = offs + N_NODES;
    // total ~56 MB

    hipMemsetAsync(counts, 0, N_NODES * sizeof(int), stream);
    // Zero pad rows (EEb row 100000, Rb row 400).
    hipMemsetAsync(EEb + (size_t)ZROW * DIM, 0, DIM * sizeof(__bf16), stream);
    hipMemsetAsync(Rb + (size_t)ZREL * DIM, 0, DIM * sizeof(__bf16), stream);

    rel_tables_kernel<<<NREL2, DIM, 0, stream>>>(rel_emb, W_O_w, W_O_b, W_I_w, W_I_b,
                                                 W_R_w, W_R_b, Rb, out_rel);

    wt_build_kernel<<<(384 * DIM + 255) / 256, 256, 0, stream>>>(
        W_O_w, W_I_w, W_S_w, WTh, WTl);

    mfma_gemm_kernel<<<dim3(NBLK_X, 6), 256, 0, stream>>>(
        ent_emb, WTh, WTl, W_S_b, EEb, ent_S);

    hist_kernel<<<(N_EDGES + 255) / 256, 256, 0, stream>>>(dst, counts);
    scan1_kernel<<<SCAN_NBLK, SCAN_BLK, 0, stream>>>(counts, offs, bsum);
    scan2_kernel<<<1, 128, 0, stream>>>(bsum);
    scan3_kernel<<<SCAN_NBLK, SCAN_BLK, 0, stream>>>(offs, bsum, cursor);
    fill_kernel<<<(N_EDGES / 256) * 8, 256, 0, stream>>>(src, dst, et, cursor, sp);

    gather_kernel<<<(N_NODES + 3) / 4, 256, 0, stream>>>(offs, counts, sp, EEb, Rb,
                                                         ent_S, out_ent);
}

// Round 13
// 190.343 us; speedup vs baseline: 1.2197x; 1.0030x over previous
//
#include <hip/hip_runtime.h>
#include <hip/hip_bf16.h>

#define N_NODES 50000
#define N_EDGES 800000
#define DIM 128
#define NUM_REL 200
#define NREL2 (2 * NUM_REL)
#define SCAN_BLK 512
#define SCAN_NBLK ((N_NODES + SCAN_BLK - 1) / SCAN_BLK)  // 98
#define NROWG (N_NODES / 16)   // 3125 row groups of 16 nodes
#define RG_PER_WAVE 5
#define RG_PER_BLK 20          // 4 waves x 5 rgs
#define NBLK_X ((NROWG + RG_PER_BLK - 1) / RG_PER_BLK)  // 157
#define NODES_PER_XCD (N_NODES / 8)  // 6250
// Zero-row padding: EEb row 100000 and Rb row 400 are all-zero.
#define ZROW (2 * N_NODES)
#define ZREL NREL2
#define ZPAY (ZROW | (ZREL << 17))

typedef __bf16 bf16x8 __attribute__((ext_vector_type(8)));
typedef float f32x4 __attribute__((ext_vector_type(4)));

// ---------------------------------------------------------------------------
// Kernel A: merged relation table Rb[401][128] in bf16 (W_O rel-half +b for
// t<200, W_I rel-half +b else; row 400 zeroed by memset) and rel_new output
// (rel_emb @ W_R^T + b_R, fp32).
// ---------------------------------------------------------------------------
__global__ void rel_tables_kernel(const float* __restrict__ rel_emb,
                                  const float* __restrict__ W_O_w,
                                  const float* __restrict__ W_O_b,
                                  const float* __restrict__ W_I_w,
                                  const float* __restrict__ W_I_b,
                                  const float* __restrict__ W_R_w,
                                  const float* __restrict__ W_R_b,
                                  __bf16* __restrict__ Rb,
                                  float* __restrict__ rel_new) {
    __shared__ float row[DIM];
    const int t = blockIdx.x;   // 0..399
    const int j = threadIdx.x;  // 0..127
    row[j] = rel_emb[t * DIM + j];
    __syncthreads();

    const bool fwd = (t < NUM_REL);
    const float* __restrict__ wSel = (fwd ? W_O_w : W_I_w) + j * (2 * DIM);
    const float* __restrict__ wR = W_R_w + j * DIM;

    float aSel = 0.f, aR = 0.f;
#pragma unroll 8
    for (int k = 0; k < DIM; ++k) {
        const float e = row[k];
        aSel += e * wSel[k];
        aR += e * wR[k];
    }
    Rb[t * DIM + j] = (__bf16)(aSel + (fwd ? W_O_b[j] : W_I_b[j]));
    rel_new[t * DIM + j] = aR + W_R_b[j];
}

// ---------------------------------------------------------------------------
// Weight prep: merged WT[384][128] (row j: j<128 -> W_O ent-half row j;
// j<256 -> W_I ent-half; else W_S) split into bf16 hi/lo.
// ---------------------------------------------------------------------------
__global__ void __launch_bounds__(256)
wt_build_kernel(const float* __restrict__ W_O_w, const float* __restrict__ W_I_w,
                const float* __restrict__ W_S_w,
                __bf16* __restrict__ WTh, __bf16* __restrict__ WTl) {
    const int idx = blockIdx.x * 256 + threadIdx.x;
    if (idx >= 384 * DIM) return;
    const int j = idx >> 7;
    const int k = idx & 127;
    float v;
    if (j < 128) v = W_O_w[j * (2 * DIM) + DIM + k];
    else if (j < 256) v = W_I_w[(j - 128) * (2 * DIM) + DIM + k];
    else v = W_S_w[(j - 256) * DIM + k];
    const __bf16 h = (__bf16)v;
    WTh[idx] = h;
    WTl[idx] = (__bf16)(v - (float)h);
}

// ---------------------------------------------------------------------------
// Kernel B (v12): v11 structure + ASM-PINNED register-resident B.
// The compiler rematerializes B loads per rg (VGPR_Count 116 < 212 needed,
// measured v9..v11) -> each rg paid cache-reload stalls.  Empty
// asm volatile("":"+v"(frag)) after the loads makes the values opaque so
// they MUST stay in VGPRs: B is loaded once per wave, the per-rg loop is
// {8 A-loads | convert | 48 register-only MFMAs}.
// ---------------------------------------------------------------------------
#define REP4(F) F(0) F(1) F(2) F(3)

__global__ void __launch_bounds__(256, 1)
mfma_gemm_kernel(const float* __restrict__ ent,
                 const __bf16* __restrict__ WTh, const __bf16* __restrict__ WTl,
                 const float* __restrict__ W_S_b,
                 __bf16* __restrict__ EEb, float* __restrict__ ent_S) {
    const int wv = threadIdx.x >> 6;
    const int cb = blockIdx.y;                       // 0..5, block-uniform
    const int rg0 = blockIdx.x * RG_PER_BLK + wv * RG_PER_WAVE;
    const int l = threadIdx.x & 63;
    const int r16 = l & 15;  // row (A) / col (B,D)
    const int kg = l >> 4;   // k-subgroup 0..3

    const int c0 = cb * 64;
    const __bf16* __restrict__ bb = WTh + (size_t)(c0 + r16) * DIM + kg * 8;
    const ptrdiff_t dlo = WTl - WTh;

    // ---- Load B fragments once; pin them into registers. ----
#define BDECL(s, ks)                                                           \
    bf16x8 Bh_##s##_##ks =                                                     \
        *(const bf16x8*)(bb + (size_t)(s) * 16 * DIM + (ks) * 32);             \
    bf16x8 Bl_##s##_##ks =                                                     \
        *(const bf16x8*)(bb + dlo + (size_t)(s) * 16 * DIM + (ks) * 32);
#define BROW(s) BDECL(s, 0) BDECL(s, 1) BDECL(s, 2) BDECL(s, 3)
    REP4(BROW)
#undef BROW
#undef BDECL

#define PIN8(a, b, c, d, e, f, g, h)                                           \
    asm volatile("" : "+v"(a), "+v"(b), "+v"(c), "+v"(d), "+v"(e), "+v"(f),    \
                      "+v"(g), "+v"(h));
    PIN8(Bh_0_0, Bh_0_1, Bh_0_2, Bh_0_3, Bh_1_0, Bh_1_1, Bh_1_2, Bh_1_3)
    PIN8(Bh_2_0, Bh_2_1, Bh_2_2, Bh_2_3, Bh_3_0, Bh_3_1, Bh_3_2, Bh_3_3)
    PIN8(Bl_0_0, Bl_0_1, Bl_0_2, Bl_0_3, Bl_1_0, Bl_1_1, Bl_1_2, Bl_1_3)
    PIN8(Bl_2_0, Bl_2_1, Bl_2_2, Bl_2_3, Bl_3_0, Bl_3_1, Bl_3_2, Bl_3_3)
#undef PIN8

    const int colb = (cb & 1) * 64;
    __bf16* __restrict__ obb =
        (cb < 4) ? (EEb + ((cb < 2) ? 0 : (size_t)N_NODES * DIM)) : (__bf16*)0;

#pragma unroll 1
    for (int rg = rg0; rg < rg0 + RG_PER_WAVE; ++rg) {
        if (rg >= NROWG) break;
        const float* __restrict__ aptr = ent + (size_t)(rg * 16 + r16) * DIM + kg * 8;
#define ADECL(ks)                                                              \
        bf16x8 ah##ks, al##ks;                                                 \
        {                                                                      \
            const float4 v0 = *(const float4*)(aptr + (ks) * 32);              \
            const float4 v1 = *(const float4*)(aptr + (ks) * 32 + 4);          \
            const float xs[8] = {v0.x, v0.y, v0.z, v0.w, v1.x, v1.y, v1.z, v1.w}; \
            _Pragma("unroll") for (int i = 0; i < 8; ++i) {                    \
                const __bf16 h = (__bf16)xs[i];                                \
                ah##ks[i] = h;                                                 \
                al##ks[i] = (__bf16)(xs[i] - (float)h);                        \
            }                                                                  \
        }
        REP4(ADECL)
#undef ADECL

        f32x4 p0 = {0.f, 0.f, 0.f, 0.f}, q0 = {0.f, 0.f, 0.f, 0.f};
        f32x4 p1 = {0.f, 0.f, 0.f, 0.f}, q1 = {0.f, 0.f, 0.f, 0.f};
        f32x4 p2 = {0.f, 0.f, 0.f, 0.f}, q2 = {0.f, 0.f, 0.f, 0.f};
        f32x4 p3 = {0.f, 0.f, 0.f, 0.f}, q3 = {0.f, 0.f, 0.f, 0.f};

#define KS(ks)                                                                 \
        p0 = __builtin_amdgcn_mfma_f32_16x16x32_bf16(ah##ks, Bh_0_##ks, p0, 0, 0, 0); \
        p1 = __builtin_amdgcn_mfma_f32_16x16x32_bf16(ah##ks, Bh_1_##ks, p1, 0, 0, 0); \
        p2 = __builtin_amdgcn_mfma_f32_16x16x32_bf16(ah##ks, Bh_2_##ks, p2, 0, 0, 0); \
        p3 = __builtin_amdgcn_mfma_f32_16x16x32_bf16(ah##ks, Bh_3_##ks, p3, 0, 0, 0); \
        q0 = __builtin_amdgcn_mfma_f32_16x16x32_bf16(al##ks, Bh_0_##ks, q0, 0, 0, 0); \
        q1 = __builtin_amdgcn_mfma_f32_16x16x32_bf16(al##ks, Bh_1_##ks, q1, 0, 0, 0); \
        q2 = __builtin_amdgcn_mfma_f32_16x16x32_bf16(al##ks, Bh_2_##ks, q2, 0, 0, 0); \
        q3 = __builtin_amdgcn_mfma_f32_16x16x32_bf16(al##ks, Bh_3_##ks, q3, 0, 0, 0); \
        q0 = __builtin_amdgcn_mfma_f32_16x16x32_bf16(ah##ks, Bl_0_##ks, q0, 0, 0, 0); \
        q1 = __builtin_amdgcn_mfma_f32_16x16x32_bf16(ah##ks, Bl_1_##ks, q1, 0, 0, 0); \
        q2 = __builtin_amdgcn_mfma_f32_16x16x32_bf16(ah##ks, Bl_2_##ks, q2, 0, 0, 0); \
        q3 = __builtin_amdgcn_mfma_f32_16x16x32_bf16(ah##ks, Bl_3_##ks, q3, 0, 0, 0);
        REP4(KS)
#undef KS

        const int orow = rg * 16 + kg * 4;
        if (cb < 4) {
#define ST(s, P, Q)                                                            \
            {                                                                  \
                const int col = colb + (s) * 16 + r16;                         \
                const f32x4 a = P + Q;                                         \
                obb[(size_t)(orow + 0) * DIM + col] = (__bf16)a[0];            \
                obb[(size_t)(orow + 1) * DIM + col] = (__bf16)a[1];            \
                obb[(size_t)(orow + 2) * DIM + col] = (__bf16)a[2];            \
                obb[(size_t)(orow + 3) * DIM + col] = (__bf16)a[3];            \
            }
            ST(0, p0, q0) ST(1, p1, q1) ST(2, p2, q2) ST(3, p3, q3)
#undef ST
        } else {
#define ST(s, P, Q)                                                            \
            {                                                                  \
                const int col = colb + (s) * 16 + r16;                         \
                const float bs = W_S_b[col];                                   \
                const f32x4 a = P + Q;                                         \
                ent_S[(size_t)(orow + 0) * DIM + col] = a[0] + bs;             \
                ent_S[(size_t)(orow + 1) * DIM + col] = a[1] + bs;             \
                ent_S[(size_t)(orow + 2) * DIM + col] = a[2] + bs;             \
                ent_S[(size_t)(orow + 3) * DIM + col] = a[3] + bs;             \
            }
            ST(0, p0, q0) ST(1, p1, q1) ST(2, p2, q2) ST(3, p3, q3)
#undef ST
        }
    }
}

// ---------------------------------------------------------------------------
// CSR construction: histogram -> 3-phase exclusive scan -> fill.
// ---------------------------------------------------------------------------
__global__ void __launch_bounds__(256)
hist_kernel(const int* __restrict__ dst, int* __restrict__ counts) {
    const int e = blockIdx.x * 256 + threadIdx.x;
    if (e < N_EDGES) atomicAdd(&counts[dst[e]], 1);
}

__global__ void __launch_bounds__(SCAN_BLK)
scan1_kernel(const int* __restrict__ counts, int* __restrict__ offs,
             int* __restrict__ bsum) {
    __shared__ int tmp[SCAN_BLK];
    const int i = blockIdx.x * SCAN_BLK + threadIdx.x;
    const int v = (i < N_NODES) ? counts[i] : 0;
    tmp[threadIdx.x] = v;
    __syncthreads();
    for (int off = 1; off < SCAN_BLK; off <<= 1) {
        const int t = (threadIdx.x >= off) ? tmp[threadIdx.x - off] : 0;
        __syncthreads();
        tmp[threadIdx.x] += t;
        __syncthreads();
    }
    if (i < N_NODES) offs[i] = tmp[threadIdx.x] - v;  // exclusive
    if (threadIdx.x == SCAN_BLK - 1) bsum[blockIdx.x] = tmp[SCAN_BLK - 1];
}

__global__ void __launch_bounds__(128)
scan2_kernel(int* __restrict__ bsum) {
    __shared__ int tmp[128];
    const int i = threadIdx.x;
    const int v = (i < SCAN_NBLK) ? bsum[i] : 0;
    tmp[i] = v;
    __syncthreads();
    for (int off = 1; off < 128; off <<= 1) {
        const int tv = (i >= off) ? tmp[i - off] : 0;
        __syncthreads();
        tmp[i] += tv;
        __syncthreads();
    }
    if (i < SCAN_NBLK) bsum[i] = tmp[i] - v;  // exclusive
}

// scan3 also seeds cursor = offs so fill's atomicAdd returns absolute slots.
__global__ void __launch_bounds__(SCAN_BLK)
scan3_kernel(int* __restrict__ offs, const int* __restrict__ bsum,
             int* __restrict__ cursor) {
    const int i = blockIdx.x * SCAN_BLK + threadIdx.x;
    if (i < N_NODES) {
        const int v = offs[i] + bsum[blockIdx.x];
        offs[i] = v;
        cursor[i] = v;
    }
}

// ---------------------------------------------------------------------------
// Fill v2: XCD-range-partitioned scatter.  Block b: edge chunk b>>3, node
// range r = b&7 (round-robin dispatch puts equal-r blocks on one XCD, so
// each sp/cursor cache line is written by a single XCD).  Edges read 8x
// (L3-served).  Payload: row(17b) | etype<<17 (9b).
// ---------------------------------------------------------------------------
__global__ void __launch_bounds__(256)
fill_kernel(const int* __restrict__ src, const int* __restrict__ dst,
            const int* __restrict__ et, int* __restrict__ cursor,
            int* __restrict__ sp) {
    const int b = blockIdx.x;
    const int r = b & 7;
    const int e = (b >> 3) * 256 + threadIdx.x;
    const int d = dst[e];
    const int rlo = r * NODES_PER_XCD;
    if ((unsigned)(d - rlo) < (unsigned)NODES_PER_XCD) {
        const int t = et[e];
        const int row = src[e] + ((t < NUM_REL) ? 0 : N_NODES);
        const int pos = atomicAdd(&cursor[d], 1);
        sp[pos] = row | (t << 17);
    }
}

// ---------------------------------------------------------------------------
// Gather-reduce v3: one wave per node, FOUR edges per iteration.
// Quarter-wave q = l>>4 handles edge i+q; lane m = l&15 covers 16 B (8 bf16
// cols) of the 256 B row via uint4 loads.  Invalid slots hit the all-zero
// pad rows -> branch-free.  Two-level shfl_xor(16/32) reduce, fused
// finalize: out = ent_S + acc / max(deg,1), 2x float4 store.
// ---------------------------------------------------------------------------
__global__ void __launch_bounds__(256)
gather_kernel(const int* __restrict__ offs, const int* __restrict__ counts,
              const int* __restrict__ sp, const __bf16* __restrict__ EEb,
              const __bf16* __restrict__ Rb, const float* __restrict__ ent_S,
              float* __restrict__ out_ent) {
    const int node = blockIdx.x * 4 + (threadIdx.x >> 6);
    if (node >= N_NODES) return;
    const int l = threadIdx.x & 63;
    const int q = l >> 4;   // edge slot 0..3
    const int m = l & 15;   // 16B piece of the row

    const int beg = offs[node];
    const int cnt = counts[node];

    float a0 = 0.f, a1 = 0.f, a2 = 0.f, a3 = 0.f;
    float a4 = 0.f, a5 = 0.f, a6 = 0.f, a7 = 0.f;
    const char* __restrict__ Eb = (const char*)EEb + 16 * m;
    const char* __restrict__ Rp = (const char*)Rb + 16 * m;

    for (int base = 0; base < cnt; base += 64) {
        const int kk = min(64, cnt - base);
        const int myp = (base + l < cnt) ? sp[beg + base + l] : ZPAY;
#pragma unroll 2
        for (int i = 0; i < kk; i += 4) {
            const int p = __shfl(myp, i + q);
            const unsigned eoff = (unsigned)(p & 0x1FFFF) << 8;
            const unsigned roff = ((unsigned)p >> 17) << 8;
            const uint4 ev = *(const uint4*)(Eb + eoff);
            const uint4 rv = *(const uint4*)(Rp + roff);
            a0 += __uint_as_float(ev.x << 16) + __uint_as_float(rv.x << 16);
            a1 += __uint_as_float(ev.x & 0xffff0000u) +
                  __uint_as_float(rv.x & 0xffff0000u);
            a2 += __uint_as_float(ev.y << 16) + __uint_as_float(rv.y << 16);
            a3 += __uint_as_float(ev.y & 0xffff0000u) +
                  __uint_as_float(rv.y & 0xffff0000u);
            a4 += __uint_as_float(ev.z << 16) + __uint_as_float(rv.z << 16);
            a5 += __uint_as_float(ev.z & 0xffff0000u) +
                  __uint_as_float(rv.z & 0xffff0000u);
            a6 += __uint_as_float(ev.w << 16) + __uint_as_float(rv.w << 16);
            a7 += __uint_as_float(ev.w & 0xffff0000u) +
                  __uint_as_float(rv.w & 0xffff0000u);
        }
    }

#define RED(A) A += __shfl_xor(A, 16); A += __shfl_xor(A, 32);
    RED(a0) RED(a1) RED(a2) RED(a3) RED(a4) RED(a5) RED(a6) RED(a7)
#undef RED

    if (l < 16) {
        const float inv = 1.0f / fmaxf((float)cnt, 1.0f);
        const float* sp_ = ent_S + (size_t)node * DIM + 8 * m;
        const float4 s0 = *(const float4*)(sp_);
        const float4 s1 = *(const float4*)(sp_ + 4);
        float4 o0, o1;
        o0.x = s0.x + a0 * inv;
        o0.y = s0.y + a1 * inv;
        o0.z = s0.z + a2 * inv;
        o0.w = s0.w + a3 * inv;
        o1.x = s1.x + a4 * inv;
        o1.y = s1.y + a5 * inv;
        o1.z = s1.z + a6 * inv;
        o1.w = s1.w + a7 * inv;
        float* op = out_ent + (size_t)node * DIM + 8 * m;
        *(float4*)(op) = o0;
        *(float4*)(op + 4) = o1;
    }
}

extern "C" void kernel_launch(void* const* d_in, const int* in_sizes, int n_in,
                              void* d_out, int out_size, void* d_ws, size_t ws_size,
                              hipStream_t stream) {
    const int* src = (const int*)d_in[0];
    const int* dst = (const int*)d_in[1];
    const int* et = (const int*)d_in[2];
    const float* ent_emb = (const float*)d_in[3];
    const float* rel_emb = (const float*)d_in[4];
    const float* W_O_w = (const float*)d_in[5];
    const float* W_O_b = (const float*)d_in[6];
    const float* W_I_w = (const float*)d_in[7];
    const float* W_I_b = (const float*)d_in[8];
    const float* W_S_w = (const float*)d_in[9];
    const float* W_S_b = (const float*)d_in[10];
    const float* W_R_w = (const float*)d_in[11];
    const float* W_R_b = (const float*)d_in[12];

    float* out_ent = (float*)d_out;                    // [50000*128]
    float* out_rel = out_ent + (size_t)N_NODES * DIM;  // [400*128]

    // Workspace layout (floats):
    // ent_S | EEb(bf16, 100001 rows) | Rb(bf16, 401 rows) | WTh | WTl | ints
    float* wsf = (float*)d_ws;
    float* ent_S = wsf;
    wsf += (size_t)N_NODES * DIM;            // 6.4M f
    __bf16* EEb = (__bf16*)wsf;
    wsf += ((size_t)(2 * N_NODES + 1) * DIM + 1) / 2;  // 100001 rows bf16
    __bf16* Rb = (__bf16*)wsf;
    wsf += (size_t)(NREL2 + 1) * DIM / 2;    // 401 rows bf16
    __bf16* WTh = (__bf16*)wsf;
    wsf += 384 * DIM / 2;
    __bf16* WTl = (__bf16*)wsf;
    wsf += 384 * DIM / 2;
    int* counts = (int*)wsf;
    int* cursor = counts + N_NODES;
    int* bsum = cursor + N_NODES;
    int* offs = bsum + 128;
    int* sp = offs + N_NODES;
    // total ~56 MB

    hipMemsetAsync(counts, 0, N_NODES * sizeof(int), stream);
    // Zero pad rows (EEb row 100000, Rb row 400).
    hipMemsetAsync(EEb + (size_t)ZROW * DIM, 0, DIM * sizeof(__bf16), stream);
    hipMemsetAsync(Rb + (size_t)ZREL * DIM, 0, DIM * sizeof(__bf16), stream);

    rel_tables_kernel<<<NREL2, DIM, 0, stream>>>(rel_emb, W_O_w, W_O_b, W_I_w, W_I_b,
                                                 W_R_w, W_R_b, Rb, out_rel);

    wt_build_kernel<<<(384 * DIM + 255) / 256, 256, 0, stream>>>(
        W_O_w, W_I_w, W_S_w, WTh, WTl);

    mfma_gemm_kernel<<<dim3(NBLK_X, 6), 256, 0, stream>>>(
        ent_emb, WTh, WTl, W_S_b, EEb, ent_S);

    hist_kernel<<<(N_EDGES + 255) / 256, 256, 0, stream>>>(dst, counts);
    scan1_kernel<<<SCAN_NBLK, SCAN_BLK, 0, stream>>>(counts, offs, bsum);
    scan2_kernel<<<1, 128, 0, stream>>>(bsum);
    scan3_kernel<<<SCAN_NBLK, SCAN_BLK, 0, stream>>>(offs, bsum, cursor);
    fill_kernel<<<(N_EDGES / 256) * 8, 256, 0, stream>>>(src, dst, et, cursor, sp);

    gather_kernel<<<(N_NODES + 3) / 4, 256, 0, stream>>>(offs, counts, sp, EEb, Rb,
                                                         ent_S, out_ent);
}